// Round 1
// 2040.113 us; speedup vs baseline: 1.1824x; 1.1824x over previous
//
#include <hip/hip_runtime.h>

#define NPLANES 24
#define IMG 192
#define RW 194        // f16 ring stride in halfs; addr col = 3 + delta-col
#define TSTEPS 926    // wavefront t = 4*i + j
#define GRID2 186     // interior grid
#define NPIX (GRID2 * GRID2)

typedef _Float16 f16x8 __attribute__((ext_vector_type(8)));
typedef _Float16 f16x4 __attribute__((ext_vector_type(4)));
typedef _Float16 h2v   __attribute__((ext_vector_type(2)));
typedef float    f32x4 __attribute__((ext_vector_type(4)));
typedef __fp16   fp16x2 __attribute__((ext_vector_type(2)));

// Precomputed x-contribution of layer 1: b1[n] + sum_k W1[k<24][n]*xfeat[k],
// per interior pixel, f16, permuted layout [pixel][g=0..3][nt=0..5][r=0..3]
// so lane (quad,lam) of the main kernel loads its 24 C-init values as 3x16B.
__device__ _Float16 PreBuf[(unsigned long long)NPLANES * NPIX * 96];

__device__ __forceinline__ h2v pk(float a, float b) {
  union { fp16x2 p; h2v h; } u;
  u.p = __builtin_amdgcn_cvt_pkrtz(a, b);
  return u.h;
}
__device__ __forceinline__ float fast_tanh(float x) {
  float e = __expf(2.0f * x);
  return 1.0f - 2.0f / (e + 1.0f);
}

// ---------------- pre-pass: massively parallel x-half of L1 ----------------
__launch_bounds__(192)
__global__ void prepass_kernel(const float* __restrict__ x,
                               const float* __restrict__ W1g,
                               const float* __restrict__ b1g)
{
  __shared__ float xs[4][IMG];
  const int tid = threadIdx.x;
  const int plane = blockIdx.x / GRID2;
  const int a = blockIdx.x - plane * GRID2;       // interior row
  const float* __restrict__ xp = x + (size_t)plane * (IMG * IMG) + (size_t)a * IMG;
  #pragma unroll
  for (int r = 0; r < 4; ++r) xs[r][tid] = xp[r * IMG + tid];
  __syncthreads();
  if (tid >= GRID2) return;                        // interior col = tid

  float f[24];
  #pragma unroll
  for (int dy = 0; dy < 3; ++dy)
    #pragma unroll
    for (int dx = 0; dx < 7; ++dx) f[7 * dy + dx] = xs[dy][tid + dx];
  #pragma unroll
  for (int dx = 0; dx < 3; ++dx) f[21 + dx] = xs[3][tid + dx];

  float acc[96];
  #pragma unroll
  for (int n = 0; n < 96; ++n) acc[n] = b1g[n];
  #pragma unroll
  for (int k = 0; k < 24; ++k) {
    const float fk = f[k];
    const float* __restrict__ wr = W1g + k * 96;   // uniform -> s_load
    #pragma unroll
    for (int n = 0; n < 96; ++n) acc[n] = fmaf(fk, wr[n], acc[n]);
  }

  _Float16* op = PreBuf + ((size_t)plane * NPIX + (size_t)a * GRID2 + tid) * 96;
  #pragma unroll
  for (int g = 0; g < 4; ++g)
    #pragma unroll
    for (int nt = 0; nt < 6; ++nt) {
      const int n = 16 * nt + 4 * g;
      union { h2v p[2]; f16x4 v; } u;
      u.p[0] = pk(acc[n], acc[n + 1]);
      u.p[1] = pk(acc[n + 2], acc[n + 3]);
      *(f16x4*)(op + g * 24 + nt * 4) = u.v;
    }
}

// ---------------- recurrent kernel ----------------
// One block per plane, 192 threads = 3 waves, wave w owns cells 16w..16w+15
// (slot = row mod 48). P2P sync via LDS step counters as before.
// MFMA orientation is FLIPPED vs the previous version: A = weights (stationary
// in VGPRs), B = activations (per-cell column). D-col = cell, so every lane
// holds its own cell's activations with 4 consecutive n per acc -> packed b64
// inter-layer staging and a 2-shuffle L4 reduction.
// Delta features (K=24, pad 32): k=7q+u = ring row i-3+q, delta col j-3+u
// (q=0..2), k21=dl1, k22=dl2, k23=dl3 (written at previous finalize).
// Only k20 (ring[i-1][j+3], step t-1 data) is patched post-spin, directly
// into the B-fragment register.
__launch_bounds__(192)
__global__ void codec_kernel(const float* __restrict__ x,
                             const float* __restrict__ W1g, const float* __restrict__ b1g,
                             const float* __restrict__ W2g, const float* __restrict__ b2g,
                             const float* __restrict__ W3g, const float* __restrict__ b3g,
                             const float* __restrict__ W4g, const float* __restrict__ b4g,
                             float* __restrict__ ws)
{
  __shared__ __align__(16) _Float16 ringH[64 * RW];   // f16 deltas; cols 0..2 & >=189 stay 0
  __shared__ __align__(16) _Float16 featA[48 * 40];   // [cell][24 delta-feats | 8 zero pad | 8 pad]
  __shared__ __align__(16) _Float16 h1A[48 * 104];    // [cell][96 + pad]
  __shared__ __align__(16) _Float16 h2A[48 * 40];     // [cell][24 + 8 zero pad | 8 pad]
  __shared__ int   ctrL[4];
  __shared__ float wsum[3];

  const int tid  = threadIdx.x;
  const int lane = tid & 63;
  const int w    = __builtin_amdgcn_readfirstlane(tid >> 6);
  const int lam  = lane & 15;
  const int quad = lane >> 4;
  const int cell = 16 * w + lam;
  const float* __restrict__ xp = x + (size_t)blockIdx.x * (IMG * IMG);
  const _Float16* __restrict__ pre = PreBuf + (size_t)blockIdx.x * NPIX * 96;
  (void)b1g;  // folded into PreBuf

  { unsigned* z = (unsigned*)ringH; for (int u = tid; u < 64 * RW / 2; u += 192) z[u] = 0; }
  { unsigned* z = (unsigned*)featA; for (int u = tid; u < 48 * 40 / 2; u += 192) z[u] = 0; }
  { unsigned* z = (unsigned*)h2A;   for (int u = tid; u < 48 * 40 / 2; u += 192) z[u] = 0; }
  if (tid < 4) ctrL[tid] = -1;

  // ---- stationary weight fragments (A-operands), loaded once ----
  f16x8 A1[6];
  #pragma unroll
  for (int nt = 0; nt < 6; ++nt) {
    union { _Float16 h[8]; f16x8 v; } u;
    #pragma unroll
    for (int e = 0; e < 8; ++e) {
      const int k = 8 * quad + e;
      int row = 24 + k;                 // taps: orig feature 24+k
      if (k == 21) row = 47;            // dl1
      if (k == 22) row = 46;            // dl2
      if (k == 23) row = 45;            // dl3
      if (k >= 24) row = 24;            // dummy (zeroed below)
      const float v = W1g[row * 96 + 16 * nt + lam];
      u.h[e] = (k < 24) ? (_Float16)v : (_Float16)0.f;
    }
    A1[nt] = u.v;
  }
  f16x8 A2[2][3];
  #pragma unroll
  for (int mt = 0; mt < 2; ++mt)
    #pragma unroll
    for (int kt = 0; kt < 3; ++kt) {
      union { _Float16 h[8]; f16x8 v; } u;
      const int n = 16 * mt + lam;
      #pragma unroll
      for (int e = 0; e < 8; ++e) {
        const int k = 32 * kt + 8 * quad + e;
        const float v = W2g[k * 24 + ((n < 24) ? n : 0)];
        u.h[e] = (n < 24) ? (_Float16)v : (_Float16)0.f;
      }
      A2[mt][kt] = u.v;
    }
  f16x8 A3;
  {
    union { _Float16 h[8]; f16x8 v; } u;
    #pragma unroll
    for (int e = 0; e < 8; ++e) {
      const int k = 8 * quad + e;
      const float v = W3g[((k < 24) ? k : 0) * 12 + ((lam < 12) ? lam : 0)];
      u.h[e] = (k < 24 && lam < 12) ? (_Float16)v : (_Float16)0.f;
    }
    A3 = u.v;
  }
  float b2v[2][4];
  #pragma unroll
  for (int mt = 0; mt < 2; ++mt)
    #pragma unroll
    for (int r = 0; r < 4; ++r) {
      const int n = 16 * mt + 4 * quad + r;
      b2v[mt][r] = (n < 24) ? b2g[n] : 0.f;
    }
  float b3v[4], w4v4[4];
  #pragma unroll
  for (int r = 0; r < 4; ++r) {
    const int m = 4 * quad + r;
    b3v[r]  = (m < 12) ? b3g[m] : 0.f;
    w4v4[r] = (m < 12) ? W4g[m] : 0.f;
  }
  const float b4v = b4g[0];

  __syncthreads();

  // ---- per-lane recurrence state ----
  int i  = cell;             // current row of this slot
  int jj = -4 * cell - 1;    // delta col; incremented at loop top -> t - 4i
  _Float16 dl1h = (_Float16)0.f, dl2h = (_Float16)0.f;
  float xtN = 0.f, sumsq = 0.f;
  f16x8 nH0, nH1, nH2;       // prefetched Pre (layout [nt][r], this lane's quad block)
  #pragma unroll
  for (int e = 0; e < 8; ++e) {
    nH0[e] = (_Float16)0.f; nH1[e] = (_Float16)0.f; nH2[e] = (_Float16)0.f;
  }

  const int prodw  = (w == 0) ? 2 : w - 1;
  const int cellF  = cell * 40;
  const int cellH1 = cell * 104;

  // initial prefetch for t = 0
  {
    int iN = i, jN = jj + 1;
    if (jN > 185) { iN += 48; jN -= 192; }
    if (jN >= 0 && iN <= 185) {
      const _Float16* pp = pre + ((size_t)(iN * GRID2 + jN)) * 96 + quad * 24;
      nH0 = *(const f16x8*)pp;
      nH1 = *(const f16x8*)(pp + 8);
      nH2 = *(const f16x8*)(pp + 16);
      if (quad == 0) xtN = xp[(iN + 3) * IMG + (jN + 3)];
    }
  }

  for (int t = 0; t < TSTEPS; ++t) {
    jj += 1;
    if (jj > 185) { i += 48; jj -= 192; }
    const bool active = (jj >= 0) && (i <= 185);

    // consume prefetched Pre (issued last iteration)
    float curF[24];
    #pragma unroll
    for (int e = 0; e < 8; ++e) {
      curF[e]      = (float)nH0[e];
      curF[8 + e]  = (float)nH1[e];
      curF[16 + e] = (float)nH2[e];
    }
    const float xtC = xtN;

    // pre-spin tap staging: k0..19 are >= t-2 old -> covered by last step's acquire
    if (quad < 3 && active) {
      const int rbase = ((i + quad - 3) & 63) * RW + jj;
      const int dstb  = cellF + 7 * quad;
      #pragma unroll
      for (int u2 = 0; u2 < 6; ++u2) featA[dstb + u2] = ringH[rbase + u2];
      if (quad < 2) featA[dstb + 6] = ringH[rbase + 6];
    }

    // B fragment (k21..23 were written at previous finalize; k20 patched post-spin)
    f16x8 Bf = *(const f16x8*)&featA[cellF + 8 * quad];

    // issue prefetch for t+1 (latency hidden under this whole step)
    {
      int iN = i, jN = jj + 1;
      if (jN > 185) { iN += 48; jN -= 192; }
      if (jN >= 0 && iN <= 185) {
        const _Float16* pp = pre + ((size_t)(iN * GRID2 + jN)) * 96 + quad * 24;
        nH0 = *(const f16x8*)pp;
        nH1 = *(const f16x8*)(pp + 8);
        nH2 = *(const f16x8*)(pp + 16);
        if (quad == 0) xtN = xp[(iN + 3) * IMG + (jN + 3)];
      }
    }

    // point-to-point sync with producer wave: step t-1 ring data
    if (t > 0) {
      while (__hip_atomic_load(&ctrL[prodw], __ATOMIC_ACQUIRE,
                               __HIP_MEMORY_SCOPE_WORKGROUP) < t - 1) { }
    }

    // fresh tap k20 = ring[i-1][delta col j+3] (t-1 data) -> quad2 frag elem 4
    if (quad == 2 && active)
      Bf[4] = ringH[((i - 1) & 63) * RW + jj + 6];

    // ---- L1: 6 MFMA, C-init = precomputed x-half ----
    #pragma unroll
    for (int nt = 0; nt < 6; ++nt) {
      f32x4 acc = { curF[4 * nt], curF[4 * nt + 1], curF[4 * nt + 2], curF[4 * nt + 3] };
      acc = __builtin_amdgcn_mfma_f32_16x16x32_f16(A1[nt], Bf, acc, 0, 0, 0);
      union { h2v p[2]; f16x4 v; } u;
      u.p[0] = pk(fast_tanh(acc[0]), fast_tanh(acc[1]));
      u.p[1] = pk(fast_tanh(acc[2]), fast_tanh(acc[3]));
      *(f16x4*)&h1A[cellH1 + 16 * nt + 4 * quad] = u.v;   // packed b64, own cell
    }

    // ---- L2: K=96 in 3 chained MFMAs per mt ----
    const f16x8 H10 = *(const f16x8*)&h1A[cellH1 + 8 * quad];
    const f16x8 H11 = *(const f16x8*)&h1A[cellH1 + 32 + 8 * quad];
    const f16x8 H12 = *(const f16x8*)&h1A[cellH1 + 64 + 8 * quad];
    #pragma unroll
    for (int mt = 0; mt < 2; ++mt) {
      f32x4 acc = { b2v[mt][0], b2v[mt][1], b2v[mt][2], b2v[mt][3] };
      acc = __builtin_amdgcn_mfma_f32_16x16x32_f16(A2[mt][0], H10, acc, 0, 0, 0);
      acc = __builtin_amdgcn_mfma_f32_16x16x32_f16(A2[mt][1], H11, acc, 0, 0, 0);
      acc = __builtin_amdgcn_mfma_f32_16x16x32_f16(A2[mt][2], H12, acc, 0, 0, 0);
      union { h2v p[2]; f16x4 v; } u;
      u.p[0] = pk(fast_tanh(acc[0]), fast_tanh(acc[1]));
      u.p[1] = pk(fast_tanh(acc[2]), fast_tanh(acc[3]));
      if (mt == 0 || quad < 2)                  // valid n2 < 24 only
        *(f16x4*)&h2A[cellF + 16 * mt + 4 * quad] = u.v;
    }

    // ---- L3 + L4: 1 MFMA, per-lane partial dot, 2-shuffle reduce ----
    const f16x8 H2 = *(const f16x8*)&h2A[cellF + 8 * quad];
    f32x4 acc3 = { b3v[0], b3v[1], b3v[2], b3v[3] };
    acc3 = __builtin_amdgcn_mfma_f32_16x16x32_f16(A3, H2, acc3, 0, 0, 0);
    float loc = fast_tanh(acc3[0]) * w4v4[0] + fast_tanh(acc3[1]) * w4v4[1]
              + fast_tanh(acc3[2]) * w4v4[2] + fast_tanh(acc3[3]) * w4v4[3];
    loc += __shfl_xor(loc, 16, 64);
    loc += __shfl_xor(loc, 32, 64);   // all lanes: full sum for cell = lam

    // ---- finalize (quad0 owner): delta, ring, dl slots for t+1, sumsq ----
    if (quad == 0 && active) {
      const float pred = fast_tanh(loc + b4v);
      const float d = xtC - pred;
      sumsq += d * d;
      const _Float16 dh = (_Float16)d;
      ringH[(i & 63) * RW + 3 + jj] = dh;
      if (jj == 185) {       // next row of this slot starts with zero last3
        featA[cellF + 21] = (_Float16)0.f;
        h2v z2; z2[0] = (_Float16)0.f; z2[1] = (_Float16)0.f;
        *(h2v*)&featA[cellF + 22] = z2;
        dl1h = (_Float16)0.f; dl2h = (_Float16)0.f;
      } else {
        featA[cellF + 21] = dh;                 // dl1 for t+1
        h2v s2; s2[0] = dl1h; s2[1] = dl2h;     // dl2, dl3 for t+1
        *(h2v*)&featA[cellF + 22] = s2;
        dl2h = dl1h; dl1h = dh;
      }
    }

    // publish step t (release orders prior LDS writes of this wave)
    if (lane == 0)
      __hip_atomic_store(&ctrL[w], t, __ATOMIC_RELEASE, __HIP_MEMORY_SCOPE_WORKGROUP);
  }

  // reduce sumsq (only quad0 lanes nonzero)
  #pragma unroll
  for (int off = 32; off >= 1; off >>= 1) sumsq += __shfl_down(sumsq, off);
  if (lane == 0) wsum[w] = sumsq;
  __syncthreads();
  if (tid == 0) ws[blockIdx.x] = wsum[0] + wsum[1] + wsum[2];
}

__global__ void finalize_kernel(const float* __restrict__ ws, float* __restrict__ out) {
  if (threadIdx.x == 0) {
    float s = 0.0f;
    #pragma unroll
    for (int p = 0; p < NPLANES; ++p) s += ws[p];
    out[0] = sqrtf(s / 875520.0f);   // b*c*(h-2)*w = 8*3*190*192
  }
}

extern "C" void kernel_launch(void* const* d_in, const int* in_sizes, int n_in,
                              void* d_out, int out_size, void* d_ws, size_t ws_size,
                              hipStream_t stream) {
  (void)in_sizes; (void)n_in; (void)out_size; (void)ws_size;
  const float* x  = (const float*)d_in[0];
  const float* W1 = (const float*)d_in[1];
  const float* b1 = (const float*)d_in[2];
  const float* W2 = (const float*)d_in[3];
  const float* b2 = (const float*)d_in[4];
  const float* W3 = (const float*)d_in[5];
  const float* b3 = (const float*)d_in[6];
  const float* W4 = (const float*)d_in[7];
  const float* b4 = (const float*)d_in[8];
  float* ws = (float*)d_ws;

  prepass_kernel<<<NPLANES * GRID2, 192, 0, stream>>>(x, W1, b1);
  codec_kernel<<<NPLANES, 192, 0, stream>>>(x, W1, b1, W2, b2, W3, b3, W4, b4, ws);
  finalize_kernel<<<1, 64, 0, stream>>>(ws, (float*)d_out);
}

// Round 2
// 1975.862 us; speedup vs baseline: 1.2209x; 1.0325x over previous
//
#include <hip/hip_runtime.h>

#define NPLANES 24
#define IMG 192
#define RW 194        // f16 ring stride in halfs; addr col = 3 + delta-col
#define GRID2 186
#define NPIX (GRID2 * GRID2)
#define SLACK 4       // extra skew per wave boundary; fresh cross-wave data is 1+SLACK old
#define TSTEPS (926 + 11 * SLACK)   // last active t = 4*185 + 4*11 + 185 = 969

typedef _Float16 f16x8 __attribute__((ext_vector_type(8)));
typedef _Float16 f16x4 __attribute__((ext_vector_type(4)));
typedef _Float16 h2v   __attribute__((ext_vector_type(2)));
typedef float    f32x4 __attribute__((ext_vector_type(4)));
typedef __fp16   fp16x2 __attribute__((ext_vector_type(2)));

// Precomputed x-half of layer 1 (bias folded), f16, PERMUTED neuron order:
// per pixel, layout [q][nt*4+r] holding phys n = 32*(nt>>1) + 8*q + 4*(nt&1) + r.
__device__ _Float16 PreBuf[(unsigned long long)NPLANES * NPIX * 96];

__device__ __forceinline__ h2v pk(float a, float b) {
  union { fp16x2 p; h2v h; } u;
  u.p = __builtin_amdgcn_cvt_pkrtz(a, b);
  return u.h;
}
__device__ __forceinline__ float fast_tanh(float x) {
  float e = __expf(2.0f * x);
  return 1.0f - 2.0f / (e + 1.0f);
}

// ---------------- pre-pass: massively parallel x-half of L1 ----------------
__launch_bounds__(192)
__global__ void prepass_kernel(const float* __restrict__ x,
                               const float* __restrict__ W1g,
                               const float* __restrict__ b1g)
{
  __shared__ float xs[4][IMG];
  const int tid = threadIdx.x;
  const int plane = blockIdx.x / GRID2;
  const int a = blockIdx.x - plane * GRID2;
  const float* __restrict__ xp = x + (size_t)plane * (IMG * IMG) + (size_t)a * IMG;
  #pragma unroll
  for (int r = 0; r < 4; ++r) xs[r][tid] = xp[r * IMG + tid];
  __syncthreads();
  if (tid >= GRID2) return;

  float f[24];
  #pragma unroll
  for (int dy = 0; dy < 3; ++dy)
    #pragma unroll
    for (int dx = 0; dx < 7; ++dx) f[7 * dy + dx] = xs[dy][tid + dx];
  #pragma unroll
  for (int dx = 0; dx < 3; ++dx) f[21 + dx] = xs[3][tid + dx];

  float acc[96];
  #pragma unroll
  for (int n = 0; n < 96; ++n) acc[n] = b1g[n];
  #pragma unroll
  for (int k = 0; k < 24; ++k) {
    const float fk = f[k];
    const float* __restrict__ wr = W1g + k * 96;
    #pragma unroll
    for (int n = 0; n < 96; ++n) acc[n] = fmaf(fk, wr[n], acc[n]);
  }

  // permuted store: [q][nt*4+r] = acc[32*(nt>>1) + 8*q + 4*(nt&1) + r]
  _Float16* op = PreBuf + ((size_t)plane * NPIX + (size_t)a * GRID2 + tid) * 96;
  #pragma unroll
  for (int g = 0; g < 4; ++g)
    #pragma unroll
    for (int np = 0; np < 3; ++np) {          // nt pair (2np, 2np+1)
      const int nA = 32 * np + 8 * g;         // nt even -> +0
      const int nB = 32 * np + 8 * g + 4;     // nt odd  -> +4
      union { h2v p[4]; f16x8 v; } u;
      u.p[0] = pk(acc[nA], acc[nA + 1]);
      u.p[1] = pk(acc[nA + 2], acc[nA + 3]);
      u.p[2] = pk(acc[nB], acc[nB + 1]);
      u.p[3] = pk(acc[nB + 2], acc[nB + 3]);
      *(f16x8*)(op + g * 24 + np * 8) = u.v;
    }
}

// ---------------- recurrent kernel ----------------
// One block per plane, 3 waves, wave w owns cells 16w..16w+15 (slot = row mod 48).
// Whole MLP is register-resident via neuron relabeling:
//   phys h1 n  = 32*(nt>>1) + 8*q + 4*(nt&1) + r   (produced slot == L2 B-slot)
//   phys h2 n2 = 8*q + 4*mt + r                    (produced slot == L3 B-slot)
// L4 as MFMA with W4 in A-row 0: pred-sum lands in quad0 acc[0].
// Tap B-fragment built in registers from 8 direct ring reads (no staging LDS):
//   q0: [dl1,dl2,dl3, r1(c-3..c+1)] q1: [r1 c+2, r1 c+3*, r2(c-3..c+2)]
//   q2: [r2 c+3, r3(c-3..c+3)] q3: zeros.  (* = fresh, read after flag check)
// Schedule skew: t = 4i + SLACK*(i>>4) + j -> cross-wave fresh data is 1+SLACK
// steps old; flag check is non-blocking in steady state. Release = raw ds_write
// after lgkmcnt(0) (no vmcnt -> prefetch stays in flight).
__launch_bounds__(192)
__global__ void codec_kernel(const float* __restrict__ x,
                             const float* __restrict__ W1g, const float* __restrict__ b1g,
                             const float* __restrict__ W2g, const float* __restrict__ b2g,
                             const float* __restrict__ W3g, const float* __restrict__ b3g,
                             const float* __restrict__ W4g, const float* __restrict__ b4g,
                             float* __restrict__ ws)
{
  __shared__ __align__(16) _Float16 ringH[64 * RW];
  __shared__ int   ctrL[4];
  __shared__ float wsum[3];

  const int tid  = threadIdx.x;
  const int lane = tid & 63;
  const int w    = __builtin_amdgcn_readfirstlane(tid >> 6);
  const int lam  = lane & 15;
  const int quad = lane >> 4;
  const int cell = 16 * w + lam;
  const float* __restrict__ xp = x + (size_t)blockIdx.x * (IMG * IMG);
  const _Float16* __restrict__ pre = PreBuf + (size_t)blockIdx.x * NPIX * 96;
  (void)b1g;

  { unsigned* z = (unsigned*)ringH; for (int u = tid; u < 64 * RW / 2; u += 192) z[u] = 0; }
  if (tid < 4) ctrL[tid] = -1;

  // ---- stationary weight fragments ----
  f16x8 A1[6];
  #pragma unroll
  for (int nt = 0; nt < 6; ++nt) {
    union { _Float16 h[8]; f16x8 v; } u;
    const int n1 = 32 * (nt >> 1) + 8 * (lam >> 2) + 4 * (nt & 1) + (lam & 3);
    #pragma unroll
    for (int e = 0; e < 8; ++e) {
      const int k = 8 * quad + e;
      float v = 0.f;
      if (k < 24) {
        // k-slot -> original W1 row: 0..2 = dl1..3 (47,46,45); 3..9 = r1 c-3..c+3
        // (38..44); 10..16 = r2 c-3..c+3 (31..37); 17..23 = r3 c-3..c+3 (24..30)
        const int r = (k < 3) ? (47 - k) : (k < 10 ? 35 + k : (k < 17 ? 21 + k : 7 + k));
        v = W1g[r * 96 + n1];
      }
      u.h[e] = (_Float16)v;
    }
    A1[nt] = u.v;
  }
  f16x8 A2[2][3];
  #pragma unroll
  for (int mt = 0; mt < 2; ++mt) {
    const int n2 = 8 * (lam >> 2) + 4 * mt + (lam & 3);
    #pragma unroll
    for (int kt = 0; kt < 3; ++kt) {
      union { _Float16 h[8]; f16x8 v; } u;
      #pragma unroll
      for (int e = 0; e < 8; ++e) {
        const int k2 = 32 * kt + 8 * quad + e;     // phys h1 index == k-slot
        u.h[e] = (n2 < 24) ? (_Float16)W2g[k2 * 24 + n2] : (_Float16)0.f;
      }
      A2[mt][kt] = u.v;
    }
  }
  f16x8 A3;
  { union { _Float16 h[8]; f16x8 v; } u;
    #pragma unroll
    for (int e = 0; e < 8; ++e) {
      const int k3 = 8 * quad + e;                 // phys h2 index == k-slot
      u.h[e] = (k3 < 24 && lam < 12) ? (_Float16)W3g[k3 * 12 + lam] : (_Float16)0.f;
    }
    A3 = u.v; }
  f16x8 A4;
  { union { _Float16 h[8]; f16x8 v; } u;
    #pragma unroll
    for (int e = 0; e < 8; ++e) {
      const int m = 4 * quad + e;
      u.h[e] = (lam == 0 && e < 4 && m < 12) ? (_Float16)W4g[m] : (_Float16)0.f;
    }
    A4 = u.v; }

  float b2v[2][4], b3v[4];
  #pragma unroll
  for (int mt = 0; mt < 2; ++mt)
    #pragma unroll
    for (int r = 0; r < 4; ++r) {
      const int n2 = 8 * quad + 4 * mt + r;
      b2v[mt][r] = (n2 < 24) ? b2g[n2] : 0.f;
    }
  #pragma unroll
  for (int r = 0; r < 4; ++r)
    b3v[r] = (4 * quad + r < 12) ? b3g[4 * quad + r] : 0.f;
  const float b4v = b4g[0];

  __syncthreads();

  const int prodw = (w == 0) ? 2 : w - 1;
  const unsigned flagRA = (unsigned)(size_t)&ctrL[prodw];
  const unsigned flagWA = (unsigned)(size_t)&ctrL[w];
  const unsigned ringBA = (unsigned)(size_t)&ringH[0];
  const unsigned short* rhu = (const unsigned short*)ringH;
  const unsigned q3mask = (quad == 3) ? 0u : 0xFFFFFFFFu;

  int i  = cell;
  int jj = -(4 * cell + SLACK * w);   // t - (4i + SLACK*(i>>4))
  unsigned dl1 = 0, dl2 = 0, dl3 = 0;
  float sumsq = 0.f, xtN = 0.f;
  f16x8 nH0, nH1, nH2;
  { union { unsigned u[4]; f16x8 v; } z; z.u[0] = z.u[1] = z.u[2] = z.u[3] = 0;
    nH0 = z.v; nH1 = z.v; nH2 = z.v; }

  // prologue prefetch for t = 0 (only cell 0 is active)
  if (jj >= 0 && i <= 185) {
    const _Float16* pp = pre + ((size_t)(i * GRID2 + jj)) * 96 + quad * 24;
    nH0 = *(const f16x8*)pp; nH1 = *(const f16x8*)(pp + 8); nH2 = *(const f16x8*)(pp + 16);
    xtN = xp[(i + 3) * IMG + (jj + 3)];
  }

  for (int t = 0; t < TSTEPS; ++t) {
    const bool active = (jj >= 0) && (i <= 185);
    const int cb  = 3 + jj;
    const int rb1 = ((i - 1) & 63) * RW;
    const int rb2 = ((i - 2) & 63) * RW;
    const int rb3 = ((i - 3) & 63) * RW;
    const int Abase = (quad == 0) ? (rb1 + cb - 3)
                    : (quad == 1) ? (rb2 + cb - 4) : (rb3 + cb - 3);
    const int Bbase = (quad == 1) ? (rb1 + cb + 2)
                    : (quad == 2) ? (rb2 + cb + 3) : Abase;

    // old taps (all >= 2+SLACK steps old at wave boundaries; in-wave in-order)
    const unsigned u0 = rhu[Bbase];
    const unsigned u1 = rhu[Abase + 0];
    const unsigned u2 = rhu[Abase + 1];
    const unsigned u3 = rhu[Abase + 2];
    const unsigned u4 = rhu[Abase + 3];
    const unsigned u5 = rhu[Abase + 4];
    const unsigned u6 = rhu[Abase + 5];
    const unsigned u7 = rhu[Abase + 6];

    // consume last iteration's prefetch BEFORE reissuing
    float curF[24];
    #pragma unroll
    for (int e = 0; e < 8; ++e) {
      curF[e]      = (float)nH0[e];
      curF[8 + e]  = (float)nH1[e];
      curF[16 + e] = (float)nH2[e];
    }
    const float xtC = xtN;

    // prefetch for next step (global; never waited by the release path)
    int iN = i, jN = jj + 1;
    if (jN > 185) { iN += 48; jN -= 192 + 3 * SLACK; }
    if (jN >= 0 && iN <= 185) {
      const _Float16* pp = pre + ((size_t)(iN * GRID2 + jN)) * 96 + quad * 24;
      nH0 = *(const f16x8*)pp; nH1 = *(const f16x8*)(pp + 8); nH2 = *(const f16x8*)(pp + 16);
      xtN = xp[(iN + 3) * IMG + (jN + 3)];
    }

    // ---- non-blocking sync: flag read + fresh tap batched (in-order DS pipe:
    // if flag >= thr, the later-issued fresh read sees the producer's write) ----
    const int thr = t - 1 - SLACK;
    int cv; unsigned fresh;
    const unsigned freshA = ringBA + (unsigned)(2 * (rb1 + cb + 3));
    asm volatile("ds_read_b32 %0, %2\n\tds_read_u16 %1, %3\n\ts_waitcnt lgkmcnt(0)"
                 : "=&v"(cv), "=&v"(fresh) : "v"(flagRA), "v"(freshA) : "memory");
    if (cv < thr) {                       // rare: producer more than SLACK behind
      int g = 0;
      do {
        asm volatile("ds_read_b32 %0, %1\n\ts_waitcnt lgkmcnt(0)"
                     : "=&v"(cv) : "v"(flagRA) : "memory");
      } while (cv < thr && ++g < (1 << 14));
      asm volatile("ds_read_u16 %0, %1\n\ts_waitcnt lgkmcnt(0)"
                   : "=&v"(fresh) : "v"(freshA) : "memory");
    }

    // ---- build tap B-fragment in registers ----
    const unsigned P01 = u0 | (u1 << 16);
    const unsigned P23 = u2 | (u3 << 16);
    const unsigned P45 = u4 | (u5 << 16);
    const unsigned P67 = u6 | (u7 << 16);
    const unsigned Pd  = dl1 | (dl2 << 16);
    const unsigned Pd3 = dl3 | (u1 << 16);
    const unsigned Pf  = u0 | (fresh << 16);
    union { unsigned u[4]; f16x8 v; } bf;
    bf.u[0] = (((quad == 0) ? Pd : (quad == 1) ? Pf : P01)) & q3mask;
    bf.u[1] = (((quad == 0) ? Pd3 : P23)) & q3mask;
    bf.u[2] = (((quad == 0) ? P23 : P45)) & q3mask;
    bf.u[3] = (((quad == 0) ? P45 : P67)) & q3mask;
    const f16x8 Bf = bf.v;

    // ---- L1: 6 MFMA, C-init = precomputed x-half (register-only from here) ----
    f32x4 h1a[6];
    #pragma unroll
    for (int nt = 0; nt < 6; ++nt) {
      f32x4 acc = { curF[4 * nt], curF[4 * nt + 1], curF[4 * nt + 2], curF[4 * nt + 3] };
      h1a[nt] = __builtin_amdgcn_mfma_f32_16x16x32_f16(A1[nt], Bf, acc, 0, 0, 0);
    }
    f16x8 B2f[3];
    #pragma unroll
    for (int kt = 0; kt < 3; ++kt) {
      union { h2v p[4]; f16x8 v; } u;
      u.p[0] = pk(fast_tanh(h1a[2 * kt][0]), fast_tanh(h1a[2 * kt][1]));
      u.p[1] = pk(fast_tanh(h1a[2 * kt][2]), fast_tanh(h1a[2 * kt][3]));
      u.p[2] = pk(fast_tanh(h1a[2 * kt + 1][0]), fast_tanh(h1a[2 * kt + 1][1]));
      u.p[3] = pk(fast_tanh(h1a[2 * kt + 1][2]), fast_tanh(h1a[2 * kt + 1][3]));
      B2f[kt] = u.v;
    }

    // ---- L2: 6 independent MFMA + add3 ----
    f32x4 a20, a21;
    {
      f32x4 za = { b2v[0][0], b2v[0][1], b2v[0][2], b2v[0][3] };
      f32x4 zb = { 0.f, 0.f, 0.f, 0.f };
      f32x4 zc = { 0.f, 0.f, 0.f, 0.f };
      za = __builtin_amdgcn_mfma_f32_16x16x32_f16(A2[0][0], B2f[0], za, 0, 0, 0);
      zb = __builtin_amdgcn_mfma_f32_16x16x32_f16(A2[0][1], B2f[1], zb, 0, 0, 0);
      zc = __builtin_amdgcn_mfma_f32_16x16x32_f16(A2[0][2], B2f[2], zc, 0, 0, 0);
      #pragma unroll
      for (int r = 0; r < 4; ++r) a20[r] = za[r] + zb[r] + zc[r];
    }
    {
      f32x4 za = { b2v[1][0], b2v[1][1], b2v[1][2], b2v[1][3] };
      f32x4 zb = { 0.f, 0.f, 0.f, 0.f };
      f32x4 zc = { 0.f, 0.f, 0.f, 0.f };
      za = __builtin_amdgcn_mfma_f32_16x16x32_f16(A2[1][0], B2f[0], za, 0, 0, 0);
      zb = __builtin_amdgcn_mfma_f32_16x16x32_f16(A2[1][1], B2f[1], zb, 0, 0, 0);
      zc = __builtin_amdgcn_mfma_f32_16x16x32_f16(A2[1][2], B2f[2], zc, 0, 0, 0);
      #pragma unroll
      for (int r = 0; r < 4; ++r) a21[r] = za[r] + zb[r] + zc[r];
    }
    f16x8 B3f;
    { union { h2v p[4]; f16x8 v; } u;
      u.p[0] = pk(fast_tanh(a20[0]), fast_tanh(a20[1]));
      u.p[1] = pk(fast_tanh(a20[2]), fast_tanh(a20[3]));
      u.p[2] = pk(fast_tanh(a21[0]), fast_tanh(a21[1]));
      u.p[3] = pk(fast_tanh(a21[2]), fast_tanh(a21[3]));
      B3f = u.v; }

    // ---- L3 ----
    f32x4 acc3 = { b3v[0], b3v[1], b3v[2], b3v[3] };
    acc3 = __builtin_amdgcn_mfma_f32_16x16x32_f16(A3, B3f, acc3, 0, 0, 0);

    // ---- L4 as MFMA: pred-sum lands at quad0 acc[0] ----
    f16x8 B4f;
    { union { h2v p[4]; f16x8 v; } u;
      u.p[0] = pk(fast_tanh(acc3[0]), fast_tanh(acc3[1]));
      u.p[1] = pk(fast_tanh(acc3[2]), fast_tanh(acc3[3]));
      u.p[2] = pk(0.f, 0.f);
      u.p[3] = pk(0.f, 0.f);
      B4f = u.v; }
    f32x4 acc4 = { b4v, b4v, b4v, b4v };
    acc4 = __builtin_amdgcn_mfma_f32_16x16x32_f16(A4, B4f, acc4, 0, 0, 0);

    const float pred = fast_tanh(acc4[0]);
    const float d = xtC - pred;
    union { _Float16 h; unsigned short s; } uu;
    uu.h = (_Float16)d;

    if (quad == 0 && active) {
      sumsq += d * d;
      ringH[(i & 63) * RW + cb] = uu.h;
    }
    if (active) {
      if (jj == 185) { dl1 = 0; dl2 = 0; dl3 = 0; }      // next row starts clean
      else { dl3 = dl2; dl2 = dl1; dl1 = (unsigned)uu.s; }
    }

    i = iN; jj = jN;

    // release: DS pipe is in-order per wave, but wait lgkm for safety (ring write
    // just issued); crucially NO vmcnt wait -> prefetch stays in flight.
    if (lane == 0)
      asm volatile("s_waitcnt lgkmcnt(0)\n\tds_write_b32 %0, %1"
                   :: "v"(flagWA), "v"(t) : "memory");
  }

  // reduce sumsq (only quad0 lanes nonzero)
  #pragma unroll
  for (int off = 32; off >= 1; off >>= 1) sumsq += __shfl_down(sumsq, off);
  if (lane == 0) wsum[w] = sumsq;
  __syncthreads();
  if (tid == 0) ws[blockIdx.x] = wsum[0] + wsum[1] + wsum[2];
}

__global__ void finalize_kernel(const float* __restrict__ ws, float* __restrict__ out) {
  if (threadIdx.x == 0) {
    float s = 0.0f;
    #pragma unroll
    for (int p = 0; p < NPLANES; ++p) s += ws[p];
    out[0] = sqrtf(s / 875520.0f);   // b*c*(h-2)*w = 8*3*190*192
  }
}

extern "C" void kernel_launch(void* const* d_in, const int* in_sizes, int n_in,
                              void* d_out, int out_size, void* d_ws, size_t ws_size,
                              hipStream_t stream) {
  (void)in_sizes; (void)n_in; (void)out_size; (void)ws_size;
  const float* x  = (const float*)d_in[0];
  const float* W1 = (const float*)d_in[1];
  const float* b1 = (const float*)d_in[2];
  const float* W2 = (const float*)d_in[3];
  const float* b2 = (const float*)d_in[4];
  const float* W3 = (const float*)d_in[5];
  const float* b3 = (const float*)d_in[6];
  const float* W4 = (const float*)d_in[7];
  const float* b4 = (const float*)d_in[8];
  float* ws = (float*)d_ws;

  prepass_kernel<<<NPLANES * GRID2, 192, 0, stream>>>(x, W1, b1);
  codec_kernel<<<NPLANES, 192, 0, stream>>>(x, W1, b1, W2, b2, W3, b3, W4, b4, ws);
  finalize_kernel<<<1, 64, 0, stream>>>(ws, (float*)d_out);
}